// Round 1
// baseline (548.246 us; speedup 1.0000x reference)
//
#include <hip/hip_runtime.h>
#include <math.h>

#define N_NODES 32768
#define F_IN    128
#define C_CH    4
#define H_HEADS 8
#define D_DIM   32
#define DM      256
#define E_BOND  65536
#define B_BRIDGE 8192
#define ET      (E_BOND + 2*B_BRIDGE)   // 81920
#define OUTC    1024                    // C*H*D
#define CAP     24                      // bucket capacity per dst node
#define NCOLS   1280                    // DM + OUTC combined bf16 weight rows

// ---- workspace layout (bytes) ----
#define WS_XL     0u
#define WS_PE     33554432u             // + N*DM*4 -> 4 KB
#define WS_SCORES 33558528u             // + ET*32*4 = 10.49 MB (later holds alpha)
#define WS_GSRC   44044288u             // + ET*4
#define WS_CNT    44371968u             // + N*4
#define WS_BUCKET 44503040u             // + N*CAP*4
#define WS_GMAX   47648768u             // + 4
// bf16 staging now lives PAST gmax: xb is read by the LAST kernel, so it can
// no longer overlay the scores region (scores are written in between).
#define WS_XB     47652864u             // N*128*2 = 8,388,608
#define WS_WC     56041472u             // NCOLS*128*2 = 327,680 -> end ~56.4 MB

typedef __attribute__((ext_vector_type(8))) short bf16x8;
typedef __attribute__((ext_vector_type(4))) float f32x4;

__device__ __forceinline__ unsigned enc_f32(float f) {
    unsigned u = __float_as_uint(f);
    return (u & 0x80000000u) ? ~u : (u | 0x80000000u);
}
__device__ __forceinline__ float dec_f32(unsigned u) {
    return (u & 0x80000000u) ? __uint_as_float(u & 0x7fffffffu) : __uint_as_float(~u);
}
__device__ __forceinline__ float leaky(float v) { return v >= 0.f ? v : 0.2f*v; }
__device__ __forceinline__ ushort f2bf(float f) {
    unsigned u = __float_as_uint(f);
    unsigned r = (u + 0x7fffu + ((u >> 16) & 1u)) >> 16;   // RNE
    return (ushort)r;
}

// ---------------- pe + gmax init ----------------
__global__ void pe_init_kernel(float* __restrict__ pe, unsigned* __restrict__ gmax) {
    int tid = threadIdx.x;              // 1024
    int c = tid >> 8, p = tid & 255;
    float expo = (float)(p & ~1) * (1.0f/256.0f);
    float div  = powf(10000.0f, expo);
    float arg  = (float)c / div;
    pe[tid] = (p & 1) ? cosf(arg) : sinf(arg);
    if (tid == 0) *gmax = 0u;
}

// ---------------- fp32 -> bf16 converts ----------------
__global__ __launch_bounds__(256) void cvt_x_kernel(const float* __restrict__ x,
                                                    ushort* __restrict__ xb) {
    const long i = (long)blockIdx.x*256 + threadIdx.x;    // float4 index
    float4 v = ((const float4*)x)[i];
    ushort4 o; o.x = f2bf(v.x); o.y = f2bf(v.y); o.z = f2bf(v.z); o.w = f2bf(v.w);
    ((ushort4*)xb)[i] = o;
}
__global__ __launch_bounds__(256) void cvt_w_kernel(const float* __restrict__ W_in,
                                                    const float* __restrict__ W_res,
                                                    ushort* __restrict__ wc) {
    const int i = blockIdx.x*256 + threadIdx.x;           // float4 index, 40960 total
    float4 v = (i < 8192) ? ((const float4*)W_in)[i] : ((const float4*)W_res)[i - 8192];
    ushort4 o; o.x = f2bf(v.x); o.y = f2bf(v.y); o.z = f2bf(v.z); o.w = f2bf(v.w);
    ((ushort4*)wc)[i] = o;
}

// ---------------- MFMA GEMM for xl only: xl[m,n] = sum_k xb[m,k]*W_in[n,k] ----
#define LDSK 72   // 64 + 8 pad (bf16)
__global__ __launch_bounds__(256) void mfma_gemm_xl(
        const ushort* __restrict__ xb, const ushort* __restrict__ wc,
        float* __restrict__ xl) {
    __shared__ ushort As[128*LDSK];
    __shared__ ushort Bs[128*LDSK];
    const int tid = threadIdx.x;
    const int m0 = blockIdx.x * 128;
    const int n0 = blockIdx.y * 128;           // 0 or 128 (cols of DM)
    const int lane = tid & 63, wv = tid >> 6;
    const int wm = wv & 1, wn = wv >> 1;
    const int quad = lane >> 4, l15 = lane & 15;
    const int mbase = wm*64, nbase = wn*64;
    f32x4 acc[4][4] = {};

    for (int kt = 0; kt < 2; ++kt) {
        if (kt) __syncthreads();
#pragma unroll
        for (int i = 0; i < 4; ++i) {
            int c = tid + i*256;
            int row = c >> 3, seg = c & 7;
            *(uint4*)&As[row*LDSK + seg*8] =
                *(const uint4*)(xb + (long)(m0 + row)*F_IN + kt*64 + seg*8);
        }
#pragma unroll
        for (int i = 0; i < 4; ++i) {
            int c = tid + i*256;
            int row = c >> 3, seg = c & 7;
            *(uint4*)&Bs[row*LDSK + seg*8] =
                *(const uint4*)(wc + (long)(n0 + row)*F_IN + kt*64 + seg*8);
        }
        __syncthreads();
#pragma unroll
        for (int ks = 0; ks < 2; ++ks) {
            const int ko = ks*32 + quad*8;
            bf16x8 af[4], bfr[4];
#pragma unroll
            for (int mi = 0; mi < 4; ++mi)
                af[mi] = *(const bf16x8*)&As[(mbase + mi*16 + l15)*LDSK + ko];
#pragma unroll
            for (int ni = 0; ni < 4; ++ni)
                bfr[ni] = *(const bf16x8*)&Bs[(nbase + ni*16 + l15)*LDSK + ko];
#pragma unroll
            for (int mi = 0; mi < 4; ++mi)
#pragma unroll
                for (int ni = 0; ni < 4; ++ni)
                    acc[mi][ni] = __builtin_amdgcn_mfma_f32_16x16x32_bf16(
                        af[mi], bfr[ni], acc[mi][ni], 0, 0, 0);
        }
    }

#pragma unroll
    for (int mi = 0; mi < 4; ++mi) {
        const int mrow = m0 + mbase + mi*16 + quad*4;
#pragma unroll
        for (int ni = 0; ni < 4; ++ni) {
            const int col = n0 + nbase + ni*16 + l15;
#pragma unroll
            for (int r = 0; r < 4; ++r)
                xl[(long)(mrow + r)*DM + col] = acc[mi][ni][r];
        }
    }
}

// ---------------- scores + bucket build: one wave per edge, grid-strided ----
// lane l owns floats [4l, 4l+4) of the 256-wide row: h = l>>3, d0 = (l&7)*4
__global__ __launch_bounds__(256) void scores_kernel(
        const float* __restrict__ xl, const float* __restrict__ pe,
        const int* __restrict__ ei, const int* __restrict__ bi,
        const float* __restrict__ datt, float* __restrict__ scores,
        unsigned* __restrict__ gmax, int* __restrict__ counts,
        int* __restrict__ bucket, int* __restrict__ gsrc) {
    const int tid = threadIdx.x;
    const int l = tid & 63, wv = tid >> 6;
    const int pos = l * 4;
    const int h = l >> 3, dq = l & 7;

    // per-lane constants: pe[c][pos..] and datt[c*8+h][dq*4..] for c=0..3
    float4 pe4[4], w4[4];
#pragma unroll
    for (int c = 0; c < 4; ++c) {
        pe4[c] = *(const float4*)(pe + c*DM + pos);
        w4[c]  = *(const float4*)(datt + (c*H_HEADS + h)*D_DIM + dq*4);
    }

    float wmax = -1e30f;
    const int stride = gridDim.x * 4;
    for (int e = blockIdx.x*4 + wv; e < ET; e += stride) {
        int nA, nB, type;
        if (e < E_BOND) {
            nA = ei[e]; nB = ei[E_BOND + e]; type = 0;
        } else if (e < E_BOND + B_BRIDGE) {
            int i = e - E_BOND;
            nA = bi[B_BRIDGE + i]; nB = bi[i]; type = 1;   // dst_bridge + src_bridge[next]
        } else {
            int i = e - E_BOND - B_BRIDGE;
            nA = bi[i]; nB = bi[B_BRIDGE + i]; type = 2;   // src_bridge + dst_bridge[prev]
        }

        // fused CSR-bucket build (was build_kernel): dst/full_src per segment
        if (l == 0) {
            int dst = (type == 0) ? nB : nA;
            int fs  = (type == 0) ? nA : nB;
            gsrc[e] = ei[fs];   // bug-faithful: x_src[full_src] == xr[src_bond[full_src]]
            int slot = atomicAdd(&counts[dst], 1);
            if (slot < CAP) bucket[dst*CAP + slot] = e;
        }

        float4 a = *(const float4*)(xl + (long)nA*DM + pos);
        float4 b = *(const float4*)(xl + (long)nB*DM + pos);
        float4 s = make_float4(a.x + b.x, a.y + b.y, a.z + b.z, a.w + b.w);

        float p[4];
#pragma unroll
        for (int c = 0; c < 4; ++c) {
            int cB = (type == 0) ? c : (type == 1 ? (c+1 < 3 ? c+1 : 3)
                                                  : (c-1 > 0 ? c-1 : 0));
            bool z = (type == 1 && c == 3) || (type == 2 && c == 0);
            float4 pa = pe4[c];
            float4 pb = (cB == 0) ? pe4[0] : (cB == 1) ? pe4[1]
                       : (cB == 2) ? pe4[2] : pe4[3];
            float v0 = leaky(s.x + pa.x + pb.x);
            float v1 = leaky(s.y + pa.y + pb.y);
            float v2 = leaky(s.z + pa.z + pb.z);
            float v3 = leaky(s.w + pa.w + pb.w);
            float d = w4[c].x*v0 + w4[c].y*v1 + w4[c].z*v2 + w4[c].w*v3;
            p[c] = z ? 0.f : d;
            // reduce over the 8 lanes of this head group
            p[c] += __shfl_xor(p[c], 1);
            p[c] += __shfl_xor(p[c], 2);
            p[c] += __shfl_xor(p[c], 4);
        }
        // lanes with dq<4 write score for (c=dq, h): one 128B segment per edge
        float val = (dq == 0) ? p[0] : (dq == 1) ? p[1] : (dq == 2) ? p[2] : p[3];
        if (dq < 4) scores[(long)e*32 + dq*8 + h] = val;
        wmax = fmaxf(wmax, fmaxf(fmaxf(p[0], p[1]), fmaxf(p[2], p[3])));
    }

    // wave max (within-8 already uniform) -> block max -> global
    wmax = fmaxf(wmax, __shfl_xor(wmax, 8));
    wmax = fmaxf(wmax, __shfl_xor(wmax, 16));
    wmax = fmaxf(wmax, __shfl_xor(wmax, 32));
    __shared__ float sm[4];
    if (l == 0) sm[wv] = wmax;
    __syncthreads();
    if (tid == 0) {
        float mm = fmaxf(fmaxf(sm[0], sm[1]), fmaxf(sm[2], sm[3]));
        atomicMax(gmax, enc_f32(mm));
    }
}

// ---------------- alpha: normalize scores in-place to softmax weights -------
// block = 8 nodes x 32 ch. Each (n,ch) owns exactly the edges in bucket[n],
// and each edge has exactly one dst node -> no write races.
__global__ __launch_bounds__(256) void alpha_kernel(
        const int* __restrict__ counts, const int* __restrict__ bucket,
        const unsigned* __restrict__ gmax, float* __restrict__ scores) {
    const int t = threadIdx.x;
    const int n = blockIdx.x*8 + (t >> 5);
    const int ch = t & 31;
    const float m = dec_f32(*gmax);
    const int cnt = min(counts[n], CAP);

    float ex[CAP];
    float den = 0.f;
#pragma unroll
    for (int i = 0; i < CAP; ++i) {
        if (i < cnt) {
            int e = bucket[n*CAP + i];
            float v = __expf(scores[(long)e*32 + ch] - m);
            ex[i] = v; den += v;
        }
    }
    const float inv = 1.f / (den + 1e-16f);
#pragma unroll
    for (int i = 0; i < CAP; ++i) {
        if (i < cnt) {
            int e = bucket[n*CAP + i];
            scores[(long)e*32 + ch] = ex[i] * inv;
        }
    }
}

// ---------------- fused residual GEMM + aggregation + bias + PReLU ----------
// out[n, col] = PReLU( (x@W_res^T)[n,col] + sum_e alpha[e,ch]*(xl[g,dmc]+pe[col])
//                      + bias[col] )
// GEMM part identical to mfma_gemm_xl but B rows come from the W_res block of
// wc (row DM + n0 + r), and the epilogue walks each node's edge bucket with
// the edge index as the OUTER loop over 16 unrolled rows (16 independent load
// chains in flight -> gather latency hidden).
__global__ __launch_bounds__(256) void mfma_gemm_fused(
        const ushort* __restrict__ xb, const ushort* __restrict__ wc,
        const float* __restrict__ xl, const float* __restrict__ pe,
        const float* __restrict__ alpha, const int* __restrict__ counts,
        const int* __restrict__ bucket, const int* __restrict__ gsrc,
        const float* __restrict__ bias, const float* __restrict__ pw,
        float* __restrict__ out) {
    __shared__ ushort As[128*LDSK];
    __shared__ ushort Bs[128*LDSK];
    const int tid = threadIdx.x;
    const int m0 = blockIdx.x * 128;
    const int n0 = blockIdx.y * 128;           // col offset within OUTC
    const int lane = tid & 63, wv = tid >> 6;
    const int wm = wv & 1, wn = wv >> 1;
    const int quad = lane >> 4, l15 = lane & 15;
    const int mbase = wm*64, nbase = wn*64;
    f32x4 acc[4][4] = {};

    for (int kt = 0; kt < 2; ++kt) {
        if (kt) __syncthreads();
#pragma unroll
        for (int i = 0; i < 4; ++i) {
            int c = tid + i*256;
            int row = c >> 3, seg = c & 7;
            *(uint4*)&As[row*LDSK + seg*8] =
                *(const uint4*)(xb + (long)(m0 + row)*F_IN + kt*64 + seg*8);
        }
#pragma unroll
        for (int i = 0; i < 4; ++i) {
            int c = tid + i*256;
            int row = c >> 3, seg = c & 7;
            *(uint4*)&Bs[row*LDSK + seg*8] =
                *(const uint4*)(wc + (long)(DM + n0 + row)*F_IN + kt*64 + seg*8);
        }
        __syncthreads();
#pragma unroll
        for (int ks = 0; ks < 2; ++ks) {
            const int ko = ks*32 + quad*8;
            bf16x8 af[4], bfr[4];
#pragma unroll
            for (int mi = 0; mi < 4; ++mi)
                af[mi] = *(const bf16x8*)&As[(mbase + mi*16 + l15)*LDSK + ko];
#pragma unroll
            for (int ni = 0; ni < 4; ++ni)
                bfr[ni] = *(const bf16x8*)&Bs[(nbase + ni*16 + l15)*LDSK + ko];
#pragma unroll
            for (int mi = 0; mi < 4; ++mi)
#pragma unroll
                for (int ni = 0; ni < 4; ++ni)
                    acc[mi][ni] = __builtin_amdgcn_mfma_f32_16x16x32_bf16(
                        af[mi], bfr[ni], acc[mi][ni], 0, 0, 0);
        }
    }

    // ---- aggregation epilogue ----
    // Per-lane column constants (independent of mi/r). pe is flat [1024]:
    // pe[(col>>8)*256 + (col&255)] == pe[col].
    const int col0 = n0 + nbase + l15;
    int ch4[4], dmc4[4];
    float pv4[4], bv4[4];
#pragma unroll
    for (int ni = 0; ni < 4; ++ni) {
        const int col = col0 + ni*16;
        ch4[ni]  = col >> 5;       // same for all 16 lanes of a quad -> broadcast
        dmc4[ni] = col & 255;      // 16 consecutive -> 64B coalesced xl reads
        pv4[ni]  = pe[col];
        bv4[ni]  = bias[col];
    }

    int nr[4][4], ct[4][4];
    int mc = 0;
#pragma unroll
    for (int mi = 0; mi < 4; ++mi)
#pragma unroll
        for (int r = 0; r < 4; ++r) {
            const int n = m0 + mbase + mi*16 + quad*4 + r;
            nr[mi][r] = n;
            int cc = counts[n]; cc = cc < CAP ? cc : CAP;
            ct[mi][r] = cc;
            mc = mc > cc ? mc : cc;
        }

    for (int i = 0; i < mc; ++i) {
#pragma unroll
        for (int mi = 0; mi < 4; ++mi)
#pragma unroll
            for (int r = 0; r < 4; ++r) {
                if (i < ct[mi][r]) {
                    const int e = bucket[nr[mi][r]*CAP + i];
                    const int g = gsrc[e];
                    const float* xp = xl + (long)g*DM;
                    const float* ap = alpha + (long)e*32;
#pragma unroll
                    for (int ni = 0; ni < 4; ++ni)
                        acc[mi][ni][r] += ap[ch4[ni]] * (xp[dmc4[ni]] + pv4[ni]);
                }
            }
    }

    const float w = *pw;
#pragma unroll
    for (int mi = 0; mi < 4; ++mi)
#pragma unroll
        for (int ni = 0; ni < 4; ++ni) {
            const int col = col0 + ni*16;
#pragma unroll
            for (int r = 0; r < 4; ++r) {
                float v = acc[mi][ni][r] + bv4[ni];
                v = v >= 0.f ? v : w*v;
                out[(long)nr[mi][r]*OUTC + col] = v;
            }
        }
}

extern "C" void kernel_launch(void* const* d_in, const int* in_sizes, int n_in,
                              void* d_out, int out_size, void* d_ws, size_t ws_size,
                              hipStream_t stream) {
    const float* x     = (const float*)d_in[0];
    const int*   ei    = (const int*)d_in[1];
    const int*   bi    = (const int*)d_in[2];
    const float* W_in  = (const float*)d_in[3];
    const float* datt  = (const float*)d_in[4];
    const float* W_res = (const float*)d_in[5];
    const float* bias  = (const float*)d_in[6];
    const float* pw    = (const float*)d_in[7];
    float* out = (float*)d_out;
    char*  ws  = (char*)d_ws;

    float*    xl     = (float*)(ws + WS_XL);
    float*    pe     = (float*)(ws + WS_PE);
    float*    scores = (float*)(ws + WS_SCORES);
    int*      gsrc   = (int*)(ws + WS_GSRC);
    int*      counts = (int*)(ws + WS_CNT);
    int*      bucket = (int*)(ws + WS_BUCKET);
    unsigned* gmax   = (unsigned*)(ws + WS_GMAX);
    ushort*   xb     = (ushort*)(ws + WS_XB);
    ushort*   wc     = (ushort*)(ws + WS_WC);

    hipMemsetAsync(counts, 0, (size_t)N_NODES*4, stream);
    pe_init_kernel<<<1, 1024, 0, stream>>>(pe, gmax);
    cvt_x_kernel<<<(N_NODES*F_IN/4)/256, 256, 0, stream>>>(x, xb);
    cvt_w_kernel<<<(NCOLS*F_IN/4 + 255)/256, 256, 0, stream>>>(W_in, W_res, wc);
    {
        dim3 grid(N_NODES/128, DM/128);
        mfma_gemm_xl<<<grid, 256, 0, stream>>>(xb, wc, xl);
    }
    scores_kernel<<<2048, 256, 0, stream>>>(xl, pe, ei, bi, datt, scores, gmax,
                                            counts, bucket, gsrc);
    alpha_kernel<<<N_NODES/8, 256, 0, stream>>>(counts, bucket, gmax, scores);
    {
        dim3 grid(N_NODES/128, OUTC/128);
        mfma_gemm_fused<<<grid, 256, 0, stream>>>(xb, wc, xl, pe, scores, counts,
                                                  bucket, gsrc, bias, pw, out);
    }
}

// Round 2
// 338.151 us; speedup vs baseline: 1.6213x; 1.6213x over previous
//
#include <hip/hip_runtime.h>
#include <math.h>

#define N_NODES 32768
#define F_IN    128
#define C_CH    4
#define H_HEADS 8
#define D_DIM   32
#define DM      256
#define E_BOND  65536
#define B_BRIDGE 8192
#define ET      (E_BOND + 2*B_BRIDGE)   // 81920
#define OUTC    1024                    // C*H*D
#define CAP     24                      // bucket capacity per dst node
#define NCOLS   1280                    // DM + OUTC combined bf16 weight rows

// ---- workspace layout (bytes) ----
#define WS_XL      0u                   // N*DM*4        = 33,554,432
#define WS_PE      33554432u            // C*DM*4        = 4,096
#define WS_SCORES  33558528u            // ET*32*4       = 10,485,760 (alpha in-place)
#define WS_BUCKET2 44044288u            // N*CAP*8       = 6,291,456  (int2: e, g)
#define WS_CNT     50335744u            // N*4           = 131,072
#define WS_GMAX    50466816u            // 4 (+pad)
#define WS_RESID   50470912u            // N*OUTC*2      = 67,108,864 (f16 residual)
#define WS_XB      117579776u           // N*128*2       = 8,388,608
#define WS_WC      125968384u           // NCOLS*128*2   = 327,680  -> end ~126.3 MB

typedef __attribute__((ext_vector_type(8))) short bf16x8;
typedef __attribute__((ext_vector_type(4))) float f32x4;
typedef __attribute__((ext_vector_type(4))) _Float16 f16x4;

__device__ __forceinline__ unsigned enc_f32(float f) {
    unsigned u = __float_as_uint(f);
    return (u & 0x80000000u) ? ~u : (u | 0x80000000u);
}
__device__ __forceinline__ float dec_f32(unsigned u) {
    return (u & 0x80000000u) ? __uint_as_float(u & 0x7fffffffu) : __uint_as_float(~u);
}
__device__ __forceinline__ float leaky(float v) { return v >= 0.f ? v : 0.2f*v; }
__device__ __forceinline__ ushort f2bf(float f) {
    unsigned u = __float_as_uint(f);
    unsigned r = (u + 0x7fffu + ((u >> 16) & 1u)) >> 16;   // RNE
    return (ushort)r;
}

// ---------------- pe + gmax init ----------------
__global__ void pe_init_kernel(float* __restrict__ pe, unsigned* __restrict__ gmax) {
    int tid = threadIdx.x;              // 1024
    int c = tid >> 8, p = tid & 255;
    float expo = (float)(p & ~1) * (1.0f/256.0f);
    float div  = powf(10000.0f, expo);
    float arg  = (float)c / div;
    pe[tid] = (p & 1) ? cosf(arg) : sinf(arg);
    if (tid == 0) *gmax = 0u;
}

// ---------------- fp32 -> bf16 converts ----------------
__global__ __launch_bounds__(256) void cvt_x_kernel(const float* __restrict__ x,
                                                    ushort* __restrict__ xb) {
    const long i = (long)blockIdx.x*256 + threadIdx.x;    // float4 index
    float4 v = ((const float4*)x)[i];
    ushort4 o; o.x = f2bf(v.x); o.y = f2bf(v.y); o.z = f2bf(v.z); o.w = f2bf(v.w);
    ((ushort4*)xb)[i] = o;
}
__global__ __launch_bounds__(256) void cvt_w_kernel(const float* __restrict__ W_in,
                                                    const float* __restrict__ W_res,
                                                    ushort* __restrict__ wc) {
    const int i = blockIdx.x*256 + threadIdx.x;           // float4 index, 40960 total
    float4 v = (i < 8192) ? ((const float4*)W_in)[i] : ((const float4*)W_res)[i - 8192];
    ushort4 o; o.x = f2bf(v.x); o.y = f2bf(v.y); o.z = f2bf(v.z); o.w = f2bf(v.w);
    ((ushort4*)wc)[i] = o;
}

// ---------------- combined MFMA GEMM over 1280 cols ----------------
// cols [0,256)   -> xl (f32)        = x @ W_in^T
// cols [256,1280)-> resid (f16)     = x @ W_res^T
#define LDSK 72   // 64 + 8 pad (bf16)
__global__ __launch_bounds__(256) void mfma_gemm(
        const ushort* __restrict__ xb, const ushort* __restrict__ wc,
        float* __restrict__ xl, _Float16* __restrict__ resid) {
    __shared__ ushort As[128*LDSK];
    __shared__ ushort Bs[128*LDSK];
    const int tid = threadIdx.x;
    const int m0 = blockIdx.x * 128;
    const int n0 = blockIdx.y * 128;
    const int lane = tid & 63, wv = tid >> 6;
    const int wm = wv & 1, wn = wv >> 1;
    const int quad = lane >> 4, l15 = lane & 15;
    const int mbase = wm*64, nbase = wn*64;
    f32x4 acc[4][4] = {};

    for (int kt = 0; kt < 2; ++kt) {
        if (kt) __syncthreads();
#pragma unroll
        for (int i = 0; i < 4; ++i) {
            int c = tid + i*256;
            int row = c >> 3, seg = c & 7;
            *(uint4*)&As[row*LDSK + seg*8] =
                *(const uint4*)(xb + (long)(m0 + row)*F_IN + kt*64 + seg*8);
        }
#pragma unroll
        for (int i = 0; i < 4; ++i) {
            int c = tid + i*256;
            int row = c >> 3, seg = c & 7;
            *(uint4*)&Bs[row*LDSK + seg*8] =
                *(const uint4*)(wc + (long)(n0 + row)*F_IN + kt*64 + seg*8);
        }
        __syncthreads();
#pragma unroll
        for (int ks = 0; ks < 2; ++ks) {
            const int ko = ks*32 + quad*8;
            bf16x8 af[4], bfr[4];
#pragma unroll
            for (int mi = 0; mi < 4; ++mi)
                af[mi] = *(const bf16x8*)&As[(mbase + mi*16 + l15)*LDSK + ko];
#pragma unroll
            for (int ni = 0; ni < 4; ++ni)
                bfr[ni] = *(const bf16x8*)&Bs[(nbase + ni*16 + l15)*LDSK + ko];
#pragma unroll
            for (int mi = 0; mi < 4; ++mi)
#pragma unroll
                for (int ni = 0; ni < 4; ++ni)
                    acc[mi][ni] = __builtin_amdgcn_mfma_f32_16x16x32_bf16(
                        af[mi], bfr[ni], acc[mi][ni], 0, 0, 0);
        }
    }

    if (n0 < DM) {
#pragma unroll
        for (int mi = 0; mi < 4; ++mi) {
            const int mrow = m0 + mbase + mi*16 + quad*4;
#pragma unroll
            for (int ni = 0; ni < 4; ++ni) {
                const int col = n0 + nbase + ni*16 + l15;
#pragma unroll
                for (int r = 0; r < 4; ++r)
                    xl[(long)(mrow + r)*DM + col] = acc[mi][ni][r];
            }
        }
    } else {
        const int coloff = n0 - DM;
#pragma unroll
        for (int mi = 0; mi < 4; ++mi) {
            const int mrow = m0 + mbase + mi*16 + quad*4;
#pragma unroll
            for (int ni = 0; ni < 4; ++ni) {
                const int col = coloff + nbase + ni*16 + l15;
#pragma unroll
                for (int r = 0; r < 4; ++r)
                    resid[(long)(mrow + r)*OUTC + col] = (_Float16)acc[mi][ni][r];
            }
        }
    }
}

// ---------------- scores + bucket build: one wave per edge, grid-strided ----
// lane l owns floats [4l, 4l+4) of the 256-wide row: h = l>>3, d0 = (l&7)*4
__global__ __launch_bounds__(256) void scores_kernel(
        const float* __restrict__ xl, const float* __restrict__ pe,
        const int* __restrict__ ei, const int* __restrict__ bi,
        const float* __restrict__ datt, float* __restrict__ scores,
        unsigned* __restrict__ gmax, int* __restrict__ counts,
        int2* __restrict__ bucket2) {
    const int tid = threadIdx.x;
    const int l = tid & 63, wv = tid >> 6;
    const int pos = l * 4;
    const int h = l >> 3, dq = l & 7;

    // per-lane constants: pe[c][pos..] and datt[c*8+h][dq*4..] for c=0..3
    float4 pe4[4], w4[4];
#pragma unroll
    for (int c = 0; c < 4; ++c) {
        pe4[c] = *(const float4*)(pe + c*DM + pos);
        w4[c]  = *(const float4*)(datt + (c*H_HEADS + h)*D_DIM + dq*4);
    }

    float wmax = -1e30f;
    const int stride = gridDim.x * 4;
    for (int e = blockIdx.x*4 + wv; e < ET; e += stride) {
        int nA, nB, type;
        if (e < E_BOND) {
            nA = ei[e]; nB = ei[E_BOND + e]; type = 0;
        } else if (e < E_BOND + B_BRIDGE) {
            int i = e - E_BOND;
            nA = bi[B_BRIDGE + i]; nB = bi[i]; type = 1;   // dst_bridge + src_bridge[next]
        } else {
            int i = e - E_BOND - B_BRIDGE;
            nA = bi[i]; nB = bi[B_BRIDGE + i]; type = 2;   // src_bridge + dst_bridge[prev]
        }

        // fused CSR-bucket build: store (e, g) packed so the gather's
        // dependent-load chain is bucket2 -> {alpha, xl} (depth 2, not 3).
        if (l == 0) {
            int dst = (type == 0) ? nB : nA;
            int fs  = (type == 0) ? nA : nB;
            int g   = ei[fs];   // bug-faithful: x_src[full_src] == xr[src_bond[full_src]]
            int slot = atomicAdd(&counts[dst], 1);
            if (slot < CAP) bucket2[dst*CAP + slot] = make_int2(e, g);
        }

        float4 a = *(const float4*)(xl + (long)nA*DM + pos);
        float4 b = *(const float4*)(xl + (long)nB*DM + pos);
        float4 s = make_float4(a.x + b.x, a.y + b.y, a.z + b.z, a.w + b.w);

        float p[4];
#pragma unroll
        for (int c = 0; c < 4; ++c) {
            int cB = (type == 0) ? c : (type == 1 ? (c+1 < 3 ? c+1 : 3)
                                                  : (c-1 > 0 ? c-1 : 0));
            bool z = (type == 1 && c == 3) || (type == 2 && c == 0);
            float4 pa = pe4[c];
            float4 pb = (cB == 0) ? pe4[0] : (cB == 1) ? pe4[1]
                       : (cB == 2) ? pe4[2] : pe4[3];
            float v0 = leaky(s.x + pa.x + pb.x);
            float v1 = leaky(s.y + pa.y + pb.y);
            float v2 = leaky(s.z + pa.z + pb.z);
            float v3 = leaky(s.w + pa.w + pb.w);
            float d = w4[c].x*v0 + w4[c].y*v1 + w4[c].z*v2 + w4[c].w*v3;
            p[c] = z ? 0.f : d;
            // reduce over the 8 lanes of this head group
            p[c] += __shfl_xor(p[c], 1);
            p[c] += __shfl_xor(p[c], 2);
            p[c] += __shfl_xor(p[c], 4);
        }
        // lanes with dq<4 write score for (c=dq, h): one 128B segment per edge
        float val = (dq == 0) ? p[0] : (dq == 1) ? p[1] : (dq == 2) ? p[2] : p[3];
        if (dq < 4) scores[(long)e*32 + dq*8 + h] = val;
        wmax = fmaxf(wmax, fmaxf(fmaxf(p[0], p[1]), fmaxf(p[2], p[3])));
    }

    // wave max (within-8 already uniform) -> block max -> global
    wmax = fmaxf(wmax, __shfl_xor(wmax, 8));
    wmax = fmaxf(wmax, __shfl_xor(wmax, 16));
    wmax = fmaxf(wmax, __shfl_xor(wmax, 32));
    __shared__ float sm[4];
    if (l == 0) sm[wv] = wmax;
    __syncthreads();
    if (tid == 0) {
        float mm = fmaxf(fmaxf(sm[0], sm[1]), fmaxf(sm[2], sm[3]));
        atomicMax(gmax, enc_f32(mm));
    }
}

// ---------------- alpha: normalize scores in-place to softmax weights -------
// block = 8 nodes x 32 ch. Each (n,ch) owns exactly the edges in bucket[n],
// and each edge has exactly one dst node -> no write races.
__global__ __launch_bounds__(256) void alpha_kernel(
        const int* __restrict__ counts, const int2* __restrict__ bucket2,
        const unsigned* __restrict__ gmax, float* __restrict__ scores) {
    const int t = threadIdx.x;
    const int n = blockIdx.x*8 + (t >> 5);
    const int ch = t & 31;
    const float m = dec_f32(*gmax);
    const int cnt = min(counts[n], CAP);

    float ex[CAP];
    float den = 0.f;
#pragma unroll
    for (int i = 0; i < CAP; ++i) {
        if (i < cnt) {
            int e = bucket2[n*CAP + i].x;
            float v = __expf(scores[(long)e*32 + ch] - m);
            ex[i] = v; den += v;
        }
    }
    const float inv = 1.f / (den + 1e-16f);
#pragma unroll
    for (int i = 0; i < CAP; ++i) {
        if (i < cnt) {
            int e = bucket2[n*CAP + i].x;
            scores[(long)e*32 + ch] = ex[i] * inv;
        }
    }
}

// ---------------- gather: aggregation + f16 residual + bias + PReLU ---------
// one block per node; thread t owns (ch = t>>3, d-quad = t&7) -> 4 floats.
// per edge: int2 (e,g) -> {alpha[e*32+ch], xl[g] float4} (independent loads).
__global__ __launch_bounds__(256) void gather_kernel(
        const float* __restrict__ xl, const float* __restrict__ pe,
        const float* __restrict__ alpha, const int* __restrict__ counts,
        const int2* __restrict__ bucket2, const _Float16* __restrict__ resid,
        const float* __restrict__ bias, const float* __restrict__ pw,
        float* __restrict__ out) {
    const int n = blockIdx.x;
    const int t = threadIdx.x;
    const int ch = t >> 3;
    const int d0 = (t & 7) * 4;
    const int h = ch & 7, c = ch >> 3;
    const int cnt = min(counts[n], CAP);
    const int col = ch*D_DIM + d0;

    const float4 pv = *(const float4*)(pe + c*DM + h*D_DIM + d0);
    float4 acc = make_float4(0.f, 0.f, 0.f, 0.f);
    float asum = 0.f;

    for (int i = 0; i < cnt; ++i) {
        int2 eg = bucket2[n*CAP + i];
        float a = alpha[(long)eg.x*32 + ch];
        float4 xv = *(const float4*)(xl + (long)eg.y*DM + h*D_DIM + d0);
        acc.x += a*xv.x; acc.y += a*xv.y; acc.z += a*xv.z; acc.w += a*xv.w;
        asum += a;
    }
    // fold sum_e a*pe = pe * sum_e a
    acc.x += asum*pv.x; acc.y += asum*pv.y; acc.z += asum*pv.z; acc.w += asum*pv.w;

    const f16x4 hv = *(const f16x4*)(resid + (long)n*OUTC + col);
    const float4 b = *(const float4*)(bias + col);
    const float w = *pw;
    float r0 = acc.x + (float)hv.x + b.x;
    float r1 = acc.y + (float)hv.y + b.y;
    float r2 = acc.z + (float)hv.z + b.z;
    float r3 = acc.w + (float)hv.w + b.w;
    r0 = r0 >= 0.f ? r0 : w*r0;
    r1 = r1 >= 0.f ? r1 : w*r1;
    r2 = r2 >= 0.f ? r2 : w*r2;
    r3 = r3 >= 0.f ? r3 : w*r3;
    *(float4*)(out + (long)n*OUTC + col) = make_float4(r0, r1, r2, r3);
}

extern "C" void kernel_launch(void* const* d_in, const int* in_sizes, int n_in,
                              void* d_out, int out_size, void* d_ws, size_t ws_size,
                              hipStream_t stream) {
    const float* x     = (const float*)d_in[0];
    const int*   ei    = (const int*)d_in[1];
    const int*   bi    = (const int*)d_in[2];
    const float* W_in  = (const float*)d_in[3];
    const float* datt  = (const float*)d_in[4];
    const float* W_res = (const float*)d_in[5];
    const float* bias  = (const float*)d_in[6];
    const float* pw    = (const float*)d_in[7];
    float* out = (float*)d_out;
    char*  ws  = (char*)d_ws;

    float*     xl      = (float*)(ws + WS_XL);
    float*     pe      = (float*)(ws + WS_PE);
    float*     scores  = (float*)(ws + WS_SCORES);
    int2*      bucket2 = (int2*)(ws + WS_BUCKET2);
    int*       counts  = (int*)(ws + WS_CNT);
    unsigned*  gmax    = (unsigned*)(ws + WS_GMAX);
    _Float16*  resid   = (_Float16*)(ws + WS_RESID);
    ushort*    xb      = (ushort*)(ws + WS_XB);
    ushort*    wc      = (ushort*)(ws + WS_WC);

    hipMemsetAsync(counts, 0, (size_t)N_NODES*4, stream);
    pe_init_kernel<<<1, 1024, 0, stream>>>(pe, gmax);
    cvt_x_kernel<<<(N_NODES*F_IN/4)/256, 256, 0, stream>>>(x, xb);
    cvt_w_kernel<<<(NCOLS*F_IN/4 + 255)/256, 256, 0, stream>>>(W_in, W_res, wc);
    {
        dim3 grid(N_NODES/128, NCOLS/128);   // 256 x 10
        mfma_gemm<<<grid, 256, 0, stream>>>(xb, wc, xl, resid);
    }
    scores_kernel<<<2560, 256, 0, stream>>>(xl, pe, ei, bi, datt, scores, gmax,
                                            counts, bucket2);
    alpha_kernel<<<N_NODES/8, 256, 0, stream>>>(counts, bucket2, gmax, scores);
    gather_kernel<<<N_NODES, 256, 0, stream>>>(xl, pe, scores, counts, bucket2,
                                               resid, bias, pw, out);
}